// Round 3
// baseline (55.795 us; speedup 1.0000x reference)
//
#include <hip/hip_runtime.h>

// Attentionlayer: B=4, T=12, N=1024, F_IN=64, F_OUT=64.
//
// Identity (verified R0/R1, absmax 1.6e-2 vs threshold 1.5e-1):
//   sum(softmax(att, axis=3), axis=3) == 1 for every (b,t,n) row, so
//   res = leaky_relu(h * 1) = leaky_relu(x @ W).
//
// R2: R1 was latency-bound (VALUBusy 6.8%, occ 24%): wave-uniform x loads
// went to L2/HBM (~200-900 cyc) with too little outstanding work.
// Fix: async-stage each 32-row x tile to LDS via global_load_lds width=16
// (coalesced, no VGPR round-trip), compute from LDS broadcasts (~120 cyc,
// conflict-free), double the block count, cap VGPR for 4 waves/SIMD.

constexpr int K    = 64;             // F_IN
constexpr int C    = 64;             // F_OUT
constexpr int ROWS = 4 * 12 * 1024;  // 49152
constexpr int RPW  = 8;              // rows per wave
constexpr int WVS  = 4;              // waves per block
constexpr int RPB  = RPW * WVS;      // 32 rows per block

#define AS1C(p) (const __attribute__((address_space(1))) void*)(p)
#define AS3(p)  (__attribute__((address_space(3))) void*)(p)

__global__ __launch_bounds__(256, 4) void gat_fused_kernel(
    const float* __restrict__ x, const float* __restrict__ W,
    float* __restrict__ out) {
  __shared__ float xs[RPB * K];  // 8 KiB, linear (uniform reads: no conflicts)

  const int t    = threadIdx.x;
  const int lane = t & 63;  // output column
  const int wid  = t >> 6;  // wave id
  const int row0 = (int)blockIdx.x * RPB;

  // Async stage x tile: 32 rows x 64 f32 = 8192 B = 256 thr x 2 x 16 B.
  // Linear LDS dest (wave-uniform base + lane*16), contiguous global src.
  const float* src = x + (size_t)row0 * K;
  __builtin_amdgcn_global_load_lds(AS1C(src + t * 4),        AS3(xs + t * 4),        16, 0, 0);
  __builtin_amdgcn_global_load_lds(AS1C(src + 1024 + t * 4), AS3(xs + 1024 + t * 4), 16, 0, 0);

  // While staging is in flight: preload this lane's W column (coalesced;
  // W is 16 KiB -> L2-hot after the first blocks).
  float wc[K];
#pragma unroll
  for (int k = 0; k < K; ++k) wc[k] = W[k * C + lane];

  float acc[RPW];
#pragma unroll
  for (int r = 0; r < RPW; ++r) acc[r] = 0.f;

  __syncthreads();  // drains vmcnt -> staged tile visible

  // Wave 'wid' owns rows [wid*RPW, wid*RPW+RPW). x reads are wave-uniform
  // LDS float4 broadcasts; fully unrolled so wc/acc stay in registers.
  const float* xr = xs + wid * RPW * K;
#pragma unroll
  for (int kq = 0; kq < K / 4; ++kq) {
#pragma unroll
    for (int r = 0; r < RPW; ++r) {
      float4 v = *reinterpret_cast<const float4*>(xr + r * K + kq * 4);
      acc[r] = fmaf(v.x, wc[4 * kq + 0], acc[r]);
      acc[r] = fmaf(v.y, wc[4 * kq + 1], acc[r]);
      acc[r] = fmaf(v.z, wc[4 * kq + 2], acc[r]);
      acc[r] = fmaf(v.w, wc[4 * kq + 3], acc[r]);
    }
  }

  // leaky_relu (slope 0.01) + coalesced stores (256 B per wave-instr).
  float* ob = out + ((size_t)row0 + wid * RPW) * C + lane;
#pragma unroll
  for (int r = 0; r < RPW; ++r) {
    float a = acc[r];
    ob[r * C] = a > 0.f ? a : 0.01f * a;
  }
}

extern "C" void kernel_launch(void* const* d_in, const int* in_sizes, int n_in,
                              void* d_out, int out_size, void* d_ws, size_t ws_size,
                              hipStream_t stream) {
  // setup_inputs order: x, adj, W, a. Only x and W matter (see identity).
  const float* x = (const float*)d_in[0];
  const float* W = (const float*)d_in[2];
  float* out     = (float*)d_out;

  dim3 grid(ROWS / RPB);  // 1536 blocks
  dim3 block(256);
  gat_fused_kernel<<<grid, block, 0, stream>>>(x, W, out);
}

// Round 4
// 19.777 us; speedup vs baseline: 2.8212x; 2.8212x over previous
//
#include <hip/hip_runtime.h>

// Attentionlayer: B=4, T=12, N=1024, F_IN=64, F_OUT=64.
//
// Identity (verified R0-R2, absmax 1.6e-2 vs threshold 1.5e-1):
//   sum(softmax(att, axis=3), axis=3) == 1 for every (b,t,n) row, so
//   res = leaky_relu(h * 1) = leaky_relu(x @ W).
//
// R3: R2 spilled wc[64] to scratch (VGPR_Count 64, +93 MB WRITE = spill
// arithmetic) because the W preload was hoisted across the barrier.
// Revert to R1's no-spill compute (W loads after barrier, scheduler keeps
// live ranges short) + fix R1's latency problem: x tile staged to LDS with
// per-lane float4 loads (parallel, coalesced), compute reads x as uniform
// LDS broadcasts. Smaller tiles (32 rows) double block-level parallelism.

constexpr int K    = 64;             // F_IN
constexpr int C    = 64;             // F_OUT
constexpr int ROWS = 4 * 12 * 1024;  // 49152
constexpr int RPW  = 8;              // rows per wave
constexpr int WVS  = 4;              // waves per block
constexpr int RPB  = RPW * WVS;      // 32 rows per block

__global__ __launch_bounds__(256) void gat_fused_kernel(
    const float* __restrict__ x, const float* __restrict__ W,
    float* __restrict__ out) {
  __shared__ float xs[RPB * K];  // 8 KiB

  const int t    = threadIdx.x;
  const int lane = t & 63;  // output column
  const int wid  = t >> 6;  // wave id
  const int row0 = (int)blockIdx.x * RPB;

  // Stage x tile: 32 rows x 64 f32 = 8 KiB = 256 threads x 2 float4.
  // Per-lane coalesced loads (two independent -> MLP), stride-1 ds_writes.
  {
    const float4* src = reinterpret_cast<const float4*>(x + (size_t)row0 * K);
    float4* dst = reinterpret_cast<float4*>(xs);
    float4 v0 = src[t];
    float4 v1 = src[t + 256];
    dst[t]       = v0;
    dst[t + 256] = v1;
  }
  __syncthreads();

  // W column per lane, source-ordered right before the FMA loop so the
  // scheduler interleaves loads with uses (R1-proven: no spill, VGPR~76).
  float wc[K];
#pragma unroll
  for (int k = 0; k < K; ++k) wc[k] = W[k * C + lane];

  float acc[RPW];
#pragma unroll
  for (int r = 0; r < RPW; ++r) acc[r] = 0.f;

  // Wave 'wid' owns rows [wid*RPW, wid*RPW+RPW). x reads are wave-uniform
  // LDS float4 broadcasts (conflict-free). Fully unrolled: wc/acc stay in
  // registers (runtime-indexed register arrays go to scratch on gfx950).
  const float* xr = xs + wid * RPW * K;
#pragma unroll
  for (int kq = 0; kq < K / 4; ++kq) {
#pragma unroll
    for (int r = 0; r < RPW; ++r) {
      float4 v = *reinterpret_cast<const float4*>(xr + r * K + kq * 4);
      acc[r] = fmaf(v.x, wc[4 * kq + 0], acc[r]);
      acc[r] = fmaf(v.y, wc[4 * kq + 1], acc[r]);
      acc[r] = fmaf(v.z, wc[4 * kq + 2], acc[r]);
      acc[r] = fmaf(v.w, wc[4 * kq + 3], acc[r]);
    }
  }

  // leaky_relu (slope 0.01) + coalesced stores (256 B per wave-instr).
  float* ob = out + ((size_t)row0 + wid * RPW) * C + lane;
#pragma unroll
  for (int r = 0; r < RPW; ++r) {
    float a = acc[r];
    ob[r * C] = a > 0.f ? a : 0.01f * a;
  }
}

extern "C" void kernel_launch(void* const* d_in, const int* in_sizes, int n_in,
                              void* d_out, int out_size, void* d_ws, size_t ws_size,
                              hipStream_t stream) {
  // setup_inputs order: x, adj, W, a. Only x and W matter (see identity).
  const float* x = (const float*)d_in[0];
  const float* W = (const float*)d_in[2];
  float* out     = (float*)d_out;

  dim3 grid(ROWS / RPB);  // 1536 blocks
  dim3 block(256);
  gat_fused_kernel<<<grid, block, 0, stream>>>(x, W, out);
}

// Round 5
// 14.572 us; speedup vs baseline: 3.8288x; 1.3571x over previous
//
#include <hip/hip_runtime.h>

// Attentionlayer: B=4, T=12, N=1024, F_IN=64, F_OUT=64.
//
// Identity (verified R0-R3, absmax 1.6e-2 vs threshold 1.5e-1):
//   sum(softmax(att, axis=3), axis=3) == 1 for every (b,t,n) row, so
//   res = leaky_relu(h * 1) = leaky_relu(x @ W).
//
// R4: R3 was DS-issue-bound (128 ds_read_b128/wave x 12cyc x 24 waves/CU
// ~= 15 us, matching the plateau). Invert mapping: lane = ROW, wave = 16-col
// slice. W accesses are wave-uniform -> scalar s_load (free pipe, R0-proven
// codegen). x row read per-lane from XOR-swizzled LDS: only 16 ds_read_b128
// per thread (ds:FMA = 16:1024). Output transposed through LDS (stride-68
// pad) so global stores stay coalesced, fixing R0's 64-line strided stores.

constexpr int K    = 64;             // F_IN
constexpr int C    = 64;             // F_OUT
constexpr int ROWS = 4 * 12 * 1024;  // 49152
constexpr int TR   = 64;             // rows per block
constexpr int NC   = 16;             // cols per wave (4 waves cover 64)

__global__ __launch_bounds__(256) void gat_fused_kernel(
    const float* __restrict__ x, const float* __restrict__ W,
    float* __restrict__ out) {
  // One buffer, two phases:
  //  A: swizzled x tile, 64 rows x 16 float4-chunks (16 KB)
  //  B: output transpose tile, 64 x 68 f32 (17408 B, +4 pad vs bank stride)
  __shared__ float lds[64 * 68];

  const int t    = threadIdx.x;
  const int lane = t & 63;  // row within tile
  const int wid  = t >> 6;  // wave id -> column slice
  const int c0   = __builtin_amdgcn_readfirstlane(wid * NC);
  const int row0 = (int)blockIdx.x * TR;

  // ---- Phase A: stage x tile (64 x 64 f32), XOR-swizzled ----
  // flat float4 idx f: row = f>>4, chunk = f&15; slot = chunk ^ (row&15).
  // Both write and read are <=2-way bank aliased (free, m136).
  {
    const float4* src = reinterpret_cast<const float4*>(x + (size_t)row0 * K);
    float4* dst = reinterpret_cast<float4*>(lds);
#pragma unroll
    for (int i = 0; i < 4; ++i) {
      int f = t + i * 256;
      float4 v = src[f];              // coalesced 16B/lane
      int r = f >> 4, cch = f & 15;
      dst[r * 16 + (cch ^ (r & 15))] = v;
    }
  }
  __syncthreads();

  // ---- Compute: h[row][c0+j] = sum_k x[row][k] * W[k][c0+j] ----
  float acc[NC];
#pragma unroll
  for (int j = 0; j < NC; ++j) acc[j] = 0.f;

  const float4* xs = reinterpret_cast<const float4*>(lds);
#pragma unroll
  for (int kq = 0; kq < 16; ++kq) {
    float4 xv = xs[lane * 16 + (kq ^ (lane & 15))];  // per-lane own row
    const float* wr = W + (kq * 4) * C + c0;         // uniform -> s_load
#pragma unroll
    for (int q = 0; q < 4; ++q) {
      const float* wk = wr + q * C;
      float xq = (q == 0) ? xv.x : (q == 1) ? xv.y : (q == 2) ? xv.z : xv.w;
#pragma unroll
      for (int j = 0; j < NC; ++j)
        acc[j] = fmaf(xq, wk[j], acc[j]);  // v_fmac with 1 SGPR operand
    }
  }

  __syncthreads();  // all waves done reading the x region

  // ---- Phase B: leaky_relu + transpose via LDS + coalesced stores ----
#pragma unroll
  for (int j = 0; j < NC; ++j) {
    float a = acc[j];
    acc[j] = a > 0.f ? a : 0.01f * a;
  }
  float* orow = lds + lane * 68 + c0;  // stride 68: 8-way worst, ~140cyc/wave
#pragma unroll
  for (int q = 0; q < 4; ++q) {
    *reinterpret_cast<float4*>(orow + 4 * q) =
        make_float4(acc[4 * q + 0], acc[4 * q + 1], acc[4 * q + 2], acc[4 * q + 3]);
  }
  __syncthreads();

  float4* gdst = reinterpret_cast<float4*>(out + (size_t)row0 * C);
#pragma unroll
  for (int i = 0; i < 4; ++i) {
    int f = t + i * 256;
    int r = f >> 4, cch = f & 15;
    gdst[f] = *reinterpret_cast<const float4*>(lds + r * 68 + cch * 4);
  }
}

extern "C" void kernel_launch(void* const* d_in, const int* in_sizes, int n_in,
                              void* d_out, int out_size, void* d_ws, size_t ws_size,
                              hipStream_t stream) {
  // setup_inputs order: x, adj, W, a. Only x and W matter (see identity).
  const float* x = (const float*)d_in[0];
  const float* W = (const float*)d_in[2];
  float* out     = (float*)d_out;

  dim3 grid(ROWS / TR);  // 768 blocks
  dim3 block(256);
  gat_fused_kernel<<<grid, block, 0, stream>>>(x, W, out);
}

// Round 6
// 12.842 us; speedup vs baseline: 4.3446x; 1.1347x over previous
//
#include <hip/hip_runtime.h>

// Attentionlayer: B=4, T=12, N=1024, F_IN=64, F_OUT=64.
//
// Identity (verified R0-R4, absmax 1.6e-2 vs threshold 1.5e-1):
//   sum(softmax(att, axis=3), axis=3) == 1 for every (b,t,n) row, so
//   res = leaky_relu(h * 1) = leaky_relu(x @ W).
//
// R5: R4 (lane=row, scalar-pipe W, swizzled LDS x, LDS output transpose)
// proved the structure; remaining gap is phase-overlap at only 12 waves/CU.
// Changes: 512-thread blocks (8 waves x 8 cols -> 24 waves/CU), separate
// LDS out-tile (drops one barrier, transpose overlaps trailing compute).

constexpr int K    = 64;             // F_IN
constexpr int C    = 64;             // F_OUT
constexpr int ROWS = 4 * 12 * 1024;  // 49152
constexpr int TR   = 64;             // rows per block
constexpr int NC   = 8;              // cols per wave (8 waves cover 64)
constexpr int BT   = 512;            // block threads

__global__ __launch_bounds__(BT) void gat_fused_kernel(
    const float* __restrict__ x, const float* __restrict__ W,
    float* __restrict__ out) {
  __shared__ float4 xt[TR * 16];     // swizzled x tile, 16 KB
  __shared__ float  ot[TR * 68];     // out transpose tile (+4 pad), 17 KB

  const int t    = threadIdx.x;
  const int lane = t & 63;  // row within tile
  const int wid  = t >> 6;  // wave id 0..7 -> 8-col slice
  const int c0   = __builtin_amdgcn_readfirstlane(wid * NC);
  const int row0 = (int)blockIdx.x * TR;

  // ---- Stage x tile (64x64 f32), XOR-swizzled; 512 thr x 2 float4 ----
  {
    const float4* src = reinterpret_cast<const float4*>(x + (size_t)row0 * K);
#pragma unroll
    for (int i = 0; i < 2; ++i) {
      int f = t + i * BT;            // 0..1023
      float4 v = src[f];             // coalesced 16B/lane
      int r = f >> 4, cch = f & 15;
      xt[r * 16 + (cch ^ (r & 15))] = v;
    }
  }
  __syncthreads();

  // ---- Compute: h[row][c0+j] = sum_k x[row][k] * W[k][c0+j] ----
  float acc[NC];
#pragma unroll
  for (int j = 0; j < NC; ++j) acc[j] = 0.f;

#pragma unroll
  for (int kq = 0; kq < 16; ++kq) {
    float4 xv = xt[lane * 16 + (kq ^ (lane & 15))];  // own row, 2-way max
    const float* wr = W + (kq * 4) * C + c0;         // wave-uniform -> s_load
#pragma unroll
    for (int q = 0; q < 4; ++q) {
      const float* wk = wr + q * C;
      float xq = (q == 0) ? xv.x : (q == 1) ? xv.y : (q == 2) ? xv.z : xv.w;
#pragma unroll
      for (int j = 0; j < NC; ++j)
        acc[j] = fmaf(xq, wk[j], acc[j]);  // v_fmac, SGPR W operand
    }
  }

  // ---- leaky_relu + transpose write (separate buffer: no barrier) ----
  float* orow = ot + lane * 68 + c0;
#pragma unroll
  for (int q = 0; q < NC / 4; ++q) {
    float a0 = acc[4 * q + 0], a1 = acc[4 * q + 1];
    float a2 = acc[4 * q + 2], a3 = acc[4 * q + 3];
    *reinterpret_cast<float4*>(orow + 4 * q) =
        make_float4(a0 > 0.f ? a0 : 0.01f * a0, a1 > 0.f ? a1 : 0.01f * a1,
                    a2 > 0.f ? a2 : 0.01f * a2, a3 > 0.f ? a3 : 0.01f * a3);
  }
  __syncthreads();

  // ---- Coalesced float4 stores of the transposed tile ----
  float4* gdst = reinterpret_cast<float4*>(out + (size_t)row0 * C);
#pragma unroll
  for (int i = 0; i < 2; ++i) {
    int f = t + i * BT;
    int r = f >> 4, cch = f & 15;
    gdst[f] = *reinterpret_cast<const float4*>(ot + r * 68 + cch * 4);
  }
}

extern "C" void kernel_launch(void* const* d_in, const int* in_sizes, int n_in,
                              void* d_out, int out_size, void* d_ws, size_t ws_size,
                              hipStream_t stream) {
  // setup_inputs order: x, adj, W, a. Only x and W matter (see identity).
  const float* x = (const float*)d_in[0];
  const float* W = (const float*)d_in[2];
  float* out     = (float*)d_out;

  dim3 grid(ROWS / TR);  // 768 blocks
  dim3 block(BT);
  gat_fused_kernel<<<grid, block, 0, stream>>>(x, W, out);
}